// Round 1
// baseline (202.801 us; speedup 1.0000x reference)
//
#include <hip/hip_runtime.h>
#include <hip/hip_bf16.h>
#include <stdint.h>

// Problem constants
#define BATCH 2
#define TT 2048
#define DM 768
#define RR 4
#define M_TOK 4096          // B*T tokens
#define NFEAT 6144          // D*R*2
#define NCH 6144            // B*D*R channels
#define CHUNK 64            // scan chunk length
#define NCHUNK 32           // T / CHUNK

typedef __attribute__((ext_vector_type(8))) short short8;
typedef __attribute__((ext_vector_type(4))) float float4v;

// ---------- helpers ----------
__device__ inline float bf2f(uint32_t bits16) {
    union { uint32_t u; float f; } x; x.u = bits16 << 16; return x.f;
}

typedef const __attribute__((address_space(1))) void* gptr_t;
typedef __attribute__((address_space(3))) void* lptr_t;

__device__ inline void async_ld16(const void* g, void* l) {
    __builtin_amdgcn_global_load_lds((gptr_t)(uintptr_t)g, (lptr_t)(uintptr_t)l,
                                     16, 0, 0);
}

__device__ inline void store_c(__hip_bfloat16* C, size_t idx, float v) {
    C[idx] = __float2bfloat16(v);
}
__device__ inline void store_c(float* C, size_t idx, float v) { C[idx] = v; }

// ---------- tiny prep kernels ----------
__global__ void cast_f32_bf16(const float* __restrict__ s,
                              __hip_bfloat16* __restrict__ d, int n) {
    int i = blockIdx.x * 256 + threadIdx.x;
    if (i < n) d[i] = __float2bfloat16(s[i]);
}

__global__ void coeff_kernel(const float* __restrict__ ap,
                             const float* __restrict__ bp,
                             const float* __restrict__ cp,
                             float2* __restrict__ ac, float2* __restrict__ bc,
                             float2* __restrict__ cc, float2* __restrict__ aL) {
    int i = blockIdx.x * 256 + threadIdx.x;   // 0..3071  (d*4+r)
    if (i >= DM * RR) return;
    float ar = tanhf(ap[2 * i])     * 0.97f;
    float ai = tanhf(ap[2 * i + 1]) * 0.97f;
    ac[i] = make_float2(ar, ai);
    bc[i] = make_float2(tanhf(bp[2 * i]), tanhf(bp[2 * i + 1]));
    cc[i] = make_float2(tanhf(cp[2 * i]), tanhf(cp[2 * i + 1]));
    // a^CHUNK via 6 squarings (CHUNK = 64)
    float xr = ar, xi = ai;
    #pragma unroll
    for (int k = 0; k < 6; ++k) {
        float nr = xr * xr - xi * xi;
        float ni = 2.f * xr * xi;
        xr = nr; xi = ni;
    }
    aL[i] = make_float2(xr, xi);
}

// ---------- RMSNorm + bf16 cast: one block per token ----------
__global__ __launch_bounds__(256) void rmsnorm_kernel(
    const float* __restrict__ x, const float* __restrict__ w,
    __hip_bfloat16* __restrict__ xn) {
    int row = blockIdx.x;
    const float* xr = x + (size_t)row * DM;
    int tid = threadIdx.x;
    float v0 = xr[tid], v1 = xr[tid + 256], v2 = xr[tid + 512];
    float ss = v0 * v0 + v1 * v1 + v2 * v2;
    #pragma unroll
    for (int o = 1; o < 64; o <<= 1) ss += __shfl_xor(ss, o);
    __shared__ float wsum[4];
    if ((tid & 63) == 0) wsum[tid >> 6] = ss;
    __syncthreads();
    float tot = wsum[0] + wsum[1] + wsum[2] + wsum[3];
    float scale = rsqrtf(tot * (1.f / DM) + 1e-6f);
    size_t base = (size_t)row * DM;
    xn[base + tid]       = __float2bfloat16(v0 * scale * w[tid]);
    xn[base + tid + 256] = __float2bfloat16(v1 * scale * w[tid + 256]);
    xn[base + tid + 512] = __float2bfloat16(v2 * scale * w[tid + 512]);
}

// ---------- GEMM: C[M,N] = A[M,K] * B[N,K]^T  (bf16 in, OutT out) ----------
// 128x128 block tile, BK=64, 4 waves each 64x64, 16x16x32 bf16 MFMA,
// global_load_lds width 16, XOR-swizzled LDS chunks (16B chunk, ^= row&7).
template <typename OutT>
__global__ __launch_bounds__(256) void gemm_bt(
    const __hip_bfloat16* __restrict__ A, const __hip_bfloat16* __restrict__ B,
    OutT* __restrict__ C, int M, int N, int K) {
    __shared__ __attribute__((aligned(16))) __hip_bfloat16 lA[128 * 64];
    __shared__ __attribute__((aligned(16))) __hip_bfloat16 lB[128 * 64];
    const int tid  = threadIdx.x;
    const int lane = tid & 63;
    const int wave = tid >> 6;
    const int quad = lane >> 4;
    const int l15  = lane & 15;
    const int wm = (wave >> 1) * 64;
    const int wn = (wave & 1) * 64;
    const int m0 = blockIdx.y * 128;
    const int n0 = blockIdx.x * 128;

    float4v acc[4][4] = {};

    for (int k0 = 0; k0 < K; k0 += 64) {
        __syncthreads();
        #pragma unroll
        for (int it = 0; it < 4; ++it) {
            int p = it * 256 + tid;
            int row = p >> 3;
            int cg = (p & 7) ^ (row & 7);
            async_ld16(A + (size_t)(m0 + row) * K + k0 + cg * 8, lA + p * 8);
        }
        #pragma unroll
        for (int it = 0; it < 4; ++it) {
            int p = it * 256 + tid;
            int row = p >> 3;
            int cg = (p & 7) ^ (row & 7);
            async_ld16(B + (size_t)(n0 + row) * K + k0 + cg * 8, lB + p * 8);
        }
        __syncthreads();
        #pragma unroll
        for (int s = 0; s < 2; ++s) {
            short8 af[4], bfr[4];
            #pragma unroll
            for (int i = 0; i < 4; ++i) {
                int r = wm + i * 16 + l15;
                int c = (s * 4 + quad) ^ (r & 7);
                af[i] = *(const short8*)(lA + r * 64 + c * 8);
            }
            #pragma unroll
            for (int j = 0; j < 4; ++j) {
                int r = wn + j * 16 + l15;
                int c = (s * 4 + quad) ^ (r & 7);
                bfr[j] = *(const short8*)(lB + r * 64 + c * 8);
            }
            #pragma unroll
            for (int i = 0; i < 4; ++i)
                #pragma unroll
                for (int j = 0; j < 4; ++j)
                    acc[i][j] = __builtin_amdgcn_mfma_f32_16x16x32_bf16(
                        af[i], bfr[j], acc[i][j], 0, 0, 0);
        }
    }
    // epilogue: C/D layout col = lane&15, row = quad*4 + reg (m89-verified)
    #pragma unroll
    for (int i = 0; i < 4; ++i)
        #pragma unroll
        for (int j = 0; j < 4; ++j)
            #pragma unroll
            for (int rg = 0; rg < 4; ++rg) {
                int row = m0 + wm + i * 16 + quad * 4 + rg;
                int col = n0 + wn + j * 16 + l15;
                store_c(C, (size_t)row * N + col, acc[i][j][rg]);
            }
}

// ---------- scan pass A: local chunk scans (zero init), keep final state ----
__global__ __launch_bounds__(256) void scan_passA(
    const uint32_t* __restrict__ u,            // [B*T*3072] packed bf16 pairs
    const float2* __restrict__ ac, const float2* __restrict__ bc,
    float2* __restrict__ chunkEnd) {           // [NCHUNK][NCH]
    int c = blockIdx.x * 256 + threadIdx.x;    // channel 0..6143
    int j = blockIdx.y;                        // chunk
    int b = c >= DM * RR;
    int rem = c - b * DM * RR;
    float2 a = ac[rem], bb = bc[rem];
    float sr = 0.f, si = 0.f;
    size_t base = ((size_t)b * TT + (size_t)j * CHUNK) * (DM * RR) + rem;
    #pragma unroll 8
    for (int i = 0; i < CHUNK; ++i) {
        uint32_t uw = u[base + (size_t)i * (DM * RR)];
        float ur = bf2f(uw & 0xffffu), ui = bf2f(uw >> 16);
        float tr = bb.x * ur - bb.y * ui;
        float ti = bb.x * ui + bb.y * ur;
        float nr = a.x * sr - a.y * si + tr;
        float ni = a.x * si + a.y * sr + ti;
        sr = nr; si = ni;
    }
    chunkEnd[(size_t)j * NCH + c] = make_float2(sr, si);
}

// ---------- scan pass B: sequential carry combine across chunks ----------
__global__ __launch_bounds__(256) void scan_passB(
    const float2* __restrict__ chunkEnd, const float2* __restrict__ aLp,
    float2* __restrict__ carry) {
    int c = blockIdx.x * 256 + threadIdx.x;
    int b = c >= DM * RR;
    int rem = c - b * DM * RR;
    float2 aL = aLp[rem];
    float sr = 0.f, si = 0.f;
    for (int j = 0; j < NCHUNK; ++j) {
        carry[(size_t)j * NCH + c] = make_float2(sr, si);
        float2 e = chunkEnd[(size_t)j * NCH + c];
        float nr = aL.x * sr - aL.y * si + e.x;
        float ni = aL.x * si + aL.y * sr + e.y;
        sr = nr; si = ni;
    }
}

// ---------- scan pass C: re-scan with carry, emit y = sum_r Re(c*s) --------
__global__ __launch_bounds__(256) void scan_passC(
    const uint32_t* __restrict__ u,
    const float2* __restrict__ ac, const float2* __restrict__ bc,
    const float2* __restrict__ cc, const float2* __restrict__ carry,
    __hip_bfloat16* __restrict__ y) {          // [B*T*D]
    int c = blockIdx.x * 256 + threadIdx.x;
    int j = blockIdx.y;
    int b = c >= DM * RR;
    int rem = c - b * DM * RR;
    int d = rem >> 2;
    float2 a = ac[rem], bb = bc[rem], cf = cc[rem];
    float2 s0 = carry[(size_t)j * NCH + c];
    float sr = s0.x, si = s0.y;
    size_t ubase = ((size_t)b * TT + (size_t)j * CHUNK) * (DM * RR) + rem;
    size_t ybase = ((size_t)b * TT + (size_t)j * CHUNK) * DM + d;
    #pragma unroll 4
    for (int i = 0; i < CHUNK; ++i) {
        uint32_t uw = u[ubase + (size_t)i * (DM * RR)];
        float ur = bf2f(uw & 0xffffu), ui = bf2f(uw >> 16);
        float tr = bb.x * ur - bb.y * ui;
        float ti = bb.x * ui + bb.y * ur;
        float nr = a.x * sr - a.y * si + tr;
        float ni = a.x * si + a.y * sr + ti;
        sr = nr; si = ni;
        float contrib = cf.x * sr - cf.y * si;
        contrib += __shfl_xor(contrib, 1);
        contrib += __shfl_xor(contrib, 2);
        if ((threadIdx.x & 3) == 0)
            y[ybase + (size_t)i * DM] = __float2bfloat16(contrib);
    }
}

// ---------- launch ----------
extern "C" void kernel_launch(void* const* d_in, const int* in_sizes, int n_in,
                              void* d_out, int out_size, void* d_ws,
                              size_t ws_size, hipStream_t stream) {
    const float* x      = (const float*)d_in[0];
    const float* norm_w = (const float*)d_in[1];
    const float* W_in   = (const float*)d_in[2];
    const float* W_out  = (const float*)d_in[3];
    const float* a_p    = (const float*)d_in[4];
    const float* b_p    = (const float*)d_in[5];
    const float* c_p    = (const float*)d_in[6];
    float* out = (float*)d_out;

    char* ws = (char*)d_ws;
    size_t off = 0;
    auto alloc = [&](size_t bytes) {
        void* p = ws + off;
        off += (bytes + 255) & ~(size_t)255;
        return p;
    };
    __hip_bfloat16* Win_bf  = (__hip_bfloat16*)alloc((size_t)NFEAT * DM * 2);
    __hip_bfloat16* Wout_bf = (__hip_bfloat16*)alloc((size_t)DM * DM * 2);
    __hip_bfloat16* xn      = (__hip_bfloat16*)alloc((size_t)M_TOK * DM * 2);
    __hip_bfloat16* u       = (__hip_bfloat16*)alloc((size_t)M_TOK * NFEAT * 2);
    __hip_bfloat16* y       = (__hip_bfloat16*)alloc((size_t)M_TOK * DM * 2);
    float2* ac = (float2*)alloc((size_t)DM * RR * 8);
    float2* bc = (float2*)alloc((size_t)DM * RR * 8);
    float2* cc = (float2*)alloc((size_t)DM * RR * 8);
    float2* aL = (float2*)alloc((size_t)DM * RR * 8);
    float2* chunkEnd = (float2*)alloc((size_t)NCHUNK * NCH * 8);
    float2* carry    = (float2*)alloc((size_t)NCHUNK * NCH * 8);

    // 1. weight casts + coefficients
    {
        int n1 = NFEAT * DM;
        cast_f32_bf16<<<(n1 + 255) / 256, 256, 0, stream>>>(W_in, Win_bf, n1);
        int n2 = DM * DM;
        cast_f32_bf16<<<(n2 + 255) / 256, 256, 0, stream>>>(W_out, Wout_bf, n2);
        coeff_kernel<<<(DM * RR + 255) / 256, 256, 0, stream>>>(
            a_p, b_p, c_p, ac, bc, cc, aL);
    }
    // 2. RMSNorm -> bf16
    rmsnorm_kernel<<<M_TOK, 256, 0, stream>>>(x, norm_w, xn);
    // 3. in_proj GEMM: u[4096,6144] = xn @ W_in^T
    gemm_bt<__hip_bfloat16><<<dim3(NFEAT / 128, M_TOK / 128), 256, 0, stream>>>(
        xn, Win_bf, u, M_TOK, NFEAT, DM);
    // 4. chunked scan
    scan_passA<<<dim3(NCH / 256, NCHUNK), 256, 0, stream>>>(
        (const uint32_t*)u, ac, bc, chunkEnd);
    scan_passB<<<NCH / 256, 256, 0, stream>>>(chunkEnd, aL, carry);
    scan_passC<<<dim3(NCH / 256, NCHUNK), 256, 0, stream>>>(
        (const uint32_t*)u, ac, bc, cc, carry, y);
    // 5. out_proj GEMM: out[4096,768] = y @ W_out^T
    gemm_bt<float><<<dim3(DM / 128, M_TOK / 128), 256, 0, stream>>>(
        y, Wout_bf, out, M_TOK, DM, DM);
}

// Round 2
// 192.740 us; speedup vs baseline: 1.0522x; 1.0522x over previous
//
#include <hip/hip_runtime.h>
#include <hip/hip_bf16.h>
#include <stdint.h>

// Problem constants
#define BATCH 2
#define TT 2048
#define DM 768
#define RR 4
#define M_TOK 4096          // B*T tokens
#define NFEAT 6144          // D*R*2
#define NCH 6144            // B*D*R channels
#define CHUNK 64            // scan chunk length
#define NCHUNK 32           // T / CHUNK

typedef __attribute__((ext_vector_type(8))) short short8;
typedef __attribute__((ext_vector_type(4))) float float4v;

// ---------- helpers ----------
__device__ inline float bf2f(uint32_t bits16) {
    union { uint32_t u; float f; } x; x.u = bits16 << 16; return x.f;
}

typedef const __attribute__((address_space(1))) void* gptr_t;
typedef __attribute__((address_space(3))) void* lptr_t;

__device__ inline void async_ld16(const void* g, void* l) {
    __builtin_amdgcn_global_load_lds((gptr_t)(uintptr_t)g, (lptr_t)(uintptr_t)l,
                                     16, 0, 0);
}

__device__ inline void store_c(__hip_bfloat16* C, size_t idx, float v) {
    C[idx] = __float2bfloat16(v);
}
__device__ inline void store_c(float* C, size_t idx, float v) { C[idx] = v; }

// ---------- fused prep: cast W_in + W_out to bf16, compute coefficients ----
__global__ void prep_kernel(const float* __restrict__ W_in,
                            const float* __restrict__ W_out,
                            const float* __restrict__ ap,
                            const float* __restrict__ bp,
                            const float* __restrict__ cp,
                            __hip_bfloat16* __restrict__ Win_bf,
                            __hip_bfloat16* __restrict__ Wout_bf,
                            float2* __restrict__ ac, float2* __restrict__ bc,
                            float2* __restrict__ cc, float2* __restrict__ aL) {
    const int n1 = NFEAT * DM;
    const int n2 = DM * DM;
    int i = blockIdx.x * 256 + threadIdx.x;
    if (i < n1) Win_bf[i] = __float2bfloat16(W_in[i]);
    else if (i < n1 + n2) Wout_bf[i - n1] = __float2bfloat16(W_out[i - n1]);
    if (i < DM * RR) {
        float ar = tanhf(ap[2 * i])     * 0.97f;
        float ai = tanhf(ap[2 * i + 1]) * 0.97f;
        ac[i] = make_float2(ar, ai);
        bc[i] = make_float2(tanhf(bp[2 * i]), tanhf(bp[2 * i + 1]));
        cc[i] = make_float2(tanhf(cp[2 * i]), tanhf(cp[2 * i + 1]));
        // a^CHUNK via 6 squarings (CHUNK = 64)
        float xr = ar, xi = ai;
        #pragma unroll
        for (int k = 0; k < 6; ++k) {
            float nr = xr * xr - xi * xi;
            float ni = 2.f * xr * xi;
            xr = nr; xi = ni;
        }
        aL[i] = make_float2(xr, xi);
    }
}

// ---------- RMSNorm + bf16 cast: one block per token ----------
__global__ __launch_bounds__(256) void rmsnorm_kernel(
    const float* __restrict__ x, const float* __restrict__ w,
    __hip_bfloat16* __restrict__ xn) {
    int row = blockIdx.x;
    const float* xr = x + (size_t)row * DM;
    int tid = threadIdx.x;
    float v0 = xr[tid], v1 = xr[tid + 256], v2 = xr[tid + 512];
    float ss = v0 * v0 + v1 * v1 + v2 * v2;
    #pragma unroll
    for (int o = 1; o < 64; o <<= 1) ss += __shfl_xor(ss, o);
    __shared__ float wsum[4];
    if ((tid & 63) == 0) wsum[tid >> 6] = ss;
    __syncthreads();
    float tot = wsum[0] + wsum[1] + wsum[2] + wsum[3];
    float scale = rsqrtf(tot * (1.f / DM) + 1e-6f);
    size_t base = (size_t)row * DM;
    xn[base + tid]       = __float2bfloat16(v0 * scale * w[tid]);
    xn[base + tid + 256] = __float2bfloat16(v1 * scale * w[tid + 256]);
    xn[base + tid + 512] = __float2bfloat16(v2 * scale * w[tid + 512]);
}

// ---------- GEMM: C[M,N] = A[M,K] * B[N,K]^T  (bf16 in, OutT out) ----------
// BM x BN block tile, BK=64, 4 waves in 2x2, each wave (BM/2)x(BN/2),
// 16x16x32 bf16 MFMA, global_load_lds width 16, XOR-swizzled LDS
// (16B chunks, chunk ^= row&7; wave-uniform-base constraint preserved).
template <int BM, int BN, typename OutT>
__global__ __launch_bounds__(256) void gemm_bt(
    const __hip_bfloat16* __restrict__ A, const __hip_bfloat16* __restrict__ B,
    OutT* __restrict__ C, int M, int N, int K) {
    constexpr int MI = BM / 32;   // 16-row MFMA tiles per wave (rows)
    constexpr int NJ = BN / 32;   // per wave (cols)
    __shared__ __attribute__((aligned(16))) __hip_bfloat16 lA[BM * 64];
    __shared__ __attribute__((aligned(16))) __hip_bfloat16 lB[BN * 64];
    const int tid  = threadIdx.x;
    const int lane = tid & 63;
    const int wave = tid >> 6;
    const int quad = lane >> 4;
    const int l15  = lane & 15;
    const int wm = (wave >> 1) * (BM / 2);
    const int wn = (wave & 1) * (BN / 2);
    const int m0 = blockIdx.y * BM;
    const int n0 = blockIdx.x * BN;

    float4v acc[MI][NJ] = {};

    for (int k0 = 0; k0 < K; k0 += 64) {
        __syncthreads();
        #pragma unroll
        for (int it = 0; it < BM / 32; ++it) {
            int p = it * 256 + tid;
            int row = p >> 3;
            int cg = (p & 7) ^ (row & 7);
            async_ld16(A + (size_t)(m0 + row) * K + k0 + cg * 8, lA + p * 8);
        }
        #pragma unroll
        for (int it = 0; it < BN / 32; ++it) {
            int p = it * 256 + tid;
            int row = p >> 3;
            int cg = (p & 7) ^ (row & 7);
            async_ld16(B + (size_t)(n0 + row) * K + k0 + cg * 8, lB + p * 8);
        }
        __syncthreads();
        #pragma unroll
        for (int s = 0; s < 2; ++s) {
            short8 af[MI], bfr[NJ];
            #pragma unroll
            for (int i = 0; i < MI; ++i) {
                int r = wm + i * 16 + l15;
                int c = (s * 4 + quad) ^ (r & 7);
                af[i] = *(const short8*)(lA + r * 64 + c * 8);
            }
            #pragma unroll
            for (int j = 0; j < NJ; ++j) {
                int r = wn + j * 16 + l15;
                int c = (s * 4 + quad) ^ (r & 7);
                bfr[j] = *(const short8*)(lB + r * 64 + c * 8);
            }
            #pragma unroll
            for (int i = 0; i < MI; ++i)
                #pragma unroll
                for (int j = 0; j < NJ; ++j)
                    acc[i][j] = __builtin_amdgcn_mfma_f32_16x16x32_bf16(
                        af[i], bfr[j], acc[i][j], 0, 0, 0);
        }
    }
    // epilogue: C/D layout col = lane&15, row = quad*4 + reg (m89-verified)
    #pragma unroll
    for (int i = 0; i < MI; ++i)
        #pragma unroll
        for (int j = 0; j < NJ; ++j)
            #pragma unroll
            for (int rg = 0; rg < 4; ++rg) {
                int row = m0 + wm + i * 16 + quad * 4 + rg;
                int col = n0 + wn + j * 16 + l15;
                store_c(C, (size_t)row * N + col, acc[i][j][rg]);
            }
}

// ---------- scan pass A: local chunk scans (zero init), keep final state ----
__global__ __launch_bounds__(256) void scan_passA(
    const uint32_t* __restrict__ u,            // [B*T*3072] packed bf16 pairs
    const float2* __restrict__ ac, const float2* __restrict__ bc,
    float2* __restrict__ chunkEnd) {           // [NCHUNK][NCH]
    int c = blockIdx.x * 256 + threadIdx.x;    // channel 0..6143
    int j = blockIdx.y;                        // chunk
    int b = c >= DM * RR;
    int rem = c - b * DM * RR;
    float2 a = ac[rem], bb = bc[rem];
    float sr = 0.f, si = 0.f;
    size_t base = ((size_t)b * TT + (size_t)j * CHUNK) * (DM * RR) + rem;
    #pragma unroll 8
    for (int i = 0; i < CHUNK; ++i) {
        uint32_t uw = u[base + (size_t)i * (DM * RR)];
        float ur = bf2f(uw & 0xffffu), ui = bf2f(uw >> 16);
        float tr = bb.x * ur - bb.y * ui;
        float ti = bb.x * ui + bb.y * ur;
        float nr = a.x * sr - a.y * si + tr;
        float ni = a.x * si + a.y * sr + ti;
        sr = nr; si = ni;
    }
    chunkEnd[(size_t)j * NCH + c] = make_float2(sr, si);
}

// ---------- scan pass C: compute carry inline (ex-passB), re-scan, emit y ---
__global__ __launch_bounds__(256) void scan_passC(
    const uint32_t* __restrict__ u,
    const float2* __restrict__ ac, const float2* __restrict__ bc,
    const float2* __restrict__ cc, const float2* __restrict__ aLp,
    const float2* __restrict__ chunkEnd,
    __hip_bfloat16* __restrict__ y) {          // [B*T*D]
    int c = blockIdx.x * 256 + threadIdx.x;
    int j = blockIdx.y;
    int b = c >= DM * RR;
    int rem = c - b * DM * RR;
    int d = rem >> 2;
    float2 a = ac[rem], bb = bc[rem], cf = cc[rem];
    // carry = state entering chunk j (combine chunk-end states 0..j-1)
    float2 aL = aLp[rem];
    float sr = 0.f, si = 0.f;
    #pragma unroll 4
    for (int jj = 0; jj < j; ++jj) {
        float2 e = chunkEnd[(size_t)jj * NCH + c];
        float nr = aL.x * sr - aL.y * si + e.x;
        float ni = aL.x * si + aL.y * sr + e.y;
        sr = nr; si = ni;
    }
    size_t ubase = ((size_t)b * TT + (size_t)j * CHUNK) * (DM * RR) + rem;
    size_t ybase = ((size_t)b * TT + (size_t)j * CHUNK) * DM + d;
    #pragma unroll 4
    for (int i = 0; i < CHUNK; ++i) {
        uint32_t uw = u[ubase + (size_t)i * (DM * RR)];
        float ur = bf2f(uw & 0xffffu), ui = bf2f(uw >> 16);
        float tr = bb.x * ur - bb.y * ui;
        float ti = bb.x * ui + bb.y * ur;
        float nr = a.x * sr - a.y * si + tr;
        float ni = a.x * si + a.y * sr + ti;
        sr = nr; si = ni;
        float contrib = cf.x * sr - cf.y * si;
        contrib += __shfl_xor(contrib, 1);
        contrib += __shfl_xor(contrib, 2);
        if ((threadIdx.x & 3) == 0)
            y[ybase + (size_t)i * DM] = __float2bfloat16(contrib);
    }
}

// ---------- launch ----------
extern "C" void kernel_launch(void* const* d_in, const int* in_sizes, int n_in,
                              void* d_out, int out_size, void* d_ws,
                              size_t ws_size, hipStream_t stream) {
    const float* x      = (const float*)d_in[0];
    const float* norm_w = (const float*)d_in[1];
    const float* W_in   = (const float*)d_in[2];
    const float* W_out  = (const float*)d_in[3];
    const float* a_p    = (const float*)d_in[4];
    const float* b_p    = (const float*)d_in[5];
    const float* c_p    = (const float*)d_in[6];
    float* out = (float*)d_out;

    char* ws = (char*)d_ws;
    size_t off = 0;
    auto alloc = [&](size_t bytes) {
        void* p = ws + off;
        off += (bytes + 255) & ~(size_t)255;
        return p;
    };
    __hip_bfloat16* Win_bf  = (__hip_bfloat16*)alloc((size_t)NFEAT * DM * 2);
    __hip_bfloat16* Wout_bf = (__hip_bfloat16*)alloc((size_t)DM * DM * 2);
    __hip_bfloat16* xn      = (__hip_bfloat16*)alloc((size_t)M_TOK * DM * 2);
    __hip_bfloat16* u       = (__hip_bfloat16*)alloc((size_t)M_TOK * NFEAT * 2);
    __hip_bfloat16* y       = (__hip_bfloat16*)alloc((size_t)M_TOK * DM * 2);
    float2* ac = (float2*)alloc((size_t)DM * RR * 8);
    float2* bc = (float2*)alloc((size_t)DM * RR * 8);
    float2* cc = (float2*)alloc((size_t)DM * RR * 8);
    float2* aL = (float2*)alloc((size_t)DM * RR * 8);
    float2* chunkEnd = (float2*)alloc((size_t)NCHUNK * NCH * 8);

    // 1. fused weight casts + coefficients
    {
        int n_total = NFEAT * DM + DM * DM;
        prep_kernel<<<(n_total + 255) / 256, 256, 0, stream>>>(
            W_in, W_out, a_p, b_p, c_p, Win_bf, Wout_bf, ac, bc, cc, aL);
    }
    // 2. RMSNorm -> bf16
    rmsnorm_kernel<<<M_TOK, 256, 0, stream>>>(x, norm_w, xn);
    // 3. in_proj GEMM: u[4096,6144] = xn @ W_in^T   (128x128 tiles, 1536 blks)
    gemm_bt<128, 128, __hip_bfloat16>
        <<<dim3(NFEAT / 128, M_TOK / 128), 256, 0, stream>>>(
            xn, Win_bf, u, M_TOK, NFEAT, DM);
    // 4. chunked scan (2 passes; carry combine folded into pass C)
    scan_passA<<<dim3(NCH / 256, NCHUNK), 256, 0, stream>>>(
        (const uint32_t*)u, ac, bc, chunkEnd);
    scan_passC<<<dim3(NCH / 256, NCHUNK), 256, 0, stream>>>(
        (const uint32_t*)u, ac, bc, cc, aL, chunkEnd, y);
    // 5. out_proj GEMM: out[4096,768] = y @ W_out^T (64x64 tiles, 768 blks)
    gemm_bt<64, 64, float>
        <<<dim3(DM / 64, M_TOK / 64), 256, 0, stream>>>(
            y, Wout_bf, out, M_TOK, DM, DM);
}

// Round 4
// 192.657 us; speedup vs baseline: 1.0526x; 1.0004x over previous
//
#include <hip/hip_runtime.h>
#include <hip/hip_bf16.h>
#include <stdint.h>

// Problem constants
#define BATCH 2
#define TT 2048
#define DM 768
#define RR 4
#define M_TOK 4096          // B*T tokens
#define NFEAT 6144          // D*R*2
#define NCH 6144            // B*D*R channels
#define CHUNK 64            // scan chunk length
#define NCHUNK 32           // T / CHUNK

typedef __attribute__((ext_vector_type(8))) short short8;
typedef __attribute__((ext_vector_type(4))) float float4v;

// ---------- helpers ----------
__device__ inline float bf2f(uint32_t bits16) {
    union { uint32_t u; float f; } x; x.u = bits16 << 16; return x.f;
}

typedef const __attribute__((address_space(1))) void* gptr_t;
typedef __attribute__((address_space(3))) void* lptr_t;

__device__ inline void async_ld16(const void* g, void* l) {
    __builtin_amdgcn_global_load_lds((gptr_t)(uintptr_t)g, (lptr_t)(uintptr_t)l,
                                     16, 0, 0);
}

__device__ inline void store_c(__hip_bfloat16* C, size_t idx, float v) {
    C[idx] = __float2bfloat16(v);
}
__device__ inline void store_c(float* C, size_t idx, float v) { C[idx] = v; }

__device__ inline uint2 pack4bf(float a, float b, float c, float d) {
    union { __hip_bfloat16 h[4]; uint2 u; } o;
    o.h[0] = __float2bfloat16(a); o.h[1] = __float2bfloat16(b);
    o.h[2] = __float2bfloat16(c); o.h[3] = __float2bfloat16(d);
    return o.u;
}

// ---------- fused prep: vectorized casts + coefficients ----------
__global__ __launch_bounds__(256) void prep_kernel(
    const float* __restrict__ W_in, const float* __restrict__ W_out,
    const float* __restrict__ ap, const float* __restrict__ bp,
    const float* __restrict__ cp,
    __hip_bfloat16* __restrict__ Win_bf, __hip_bfloat16* __restrict__ Wout_bf,
    float2* __restrict__ ac, float2* __restrict__ bc,
    float2* __restrict__ cc, float2* __restrict__ aL) {
    const int N1 = NFEAT * DM / 4;   // float4 count
    const int N2 = DM * DM / 4;
    int i = blockIdx.x * 256 + threadIdx.x;
    if (i < N1) {
        float4 v = ((const float4*)W_in)[i];
        ((uint2*)Win_bf)[i] = pack4bf(v.x, v.y, v.z, v.w);
    } else if (i < N1 + N2) {
        int k = i - N1;
        float4 v = ((const float4*)W_out)[k];
        ((uint2*)Wout_bf)[k] = pack4bf(v.x, v.y, v.z, v.w);
    }
    if (i < DM * RR) {
        float ar = tanhf(ap[2 * i])     * 0.97f;
        float ai = tanhf(ap[2 * i + 1]) * 0.97f;
        ac[i] = make_float2(ar, ai);
        bc[i] = make_float2(tanhf(bp[2 * i]), tanhf(bp[2 * i + 1]));
        cc[i] = make_float2(tanhf(cp[2 * i]), tanhf(cp[2 * i + 1]));
        float xr = ar, xi = ai;   // a^CHUNK via 6 squarings
        #pragma unroll
        for (int k = 0; k < 6; ++k) {
            float nr = xr * xr - xi * xi;
            float ni = 2.f * xr * xi;
            xr = nr; xi = ni;
        }
        aL[i] = make_float2(xr, xi);
    }
}

// ---------- RMSNorm + bf16 cast: one block per token, float4 lanes ----------
__global__ __launch_bounds__(192) void rmsnorm_kernel(
    const float* __restrict__ x, const float* __restrict__ w,
    __hip_bfloat16* __restrict__ xn) {
    int row = blockIdx.x;
    int tid = threadIdx.x;                 // 0..191, 3 waves
    float4 v = ((const float4*)(x + (size_t)row * DM))[tid];
    float ss = v.x * v.x + v.y * v.y + v.z * v.z + v.w * v.w;
    #pragma unroll
    for (int o = 1; o < 64; o <<= 1) ss += __shfl_xor(ss, o);
    __shared__ float wsum[3];
    if ((tid & 63) == 0) wsum[tid >> 6] = ss;
    __syncthreads();
    float tot = wsum[0] + wsum[1] + wsum[2];
    float scale = rsqrtf(tot * (1.f / DM) + 1e-6f);
    float4 wv = ((const float4*)w)[tid];
    ((uint2*)(xn + (size_t)row * DM))[tid] =
        pack4bf(v.x * scale * wv.x, v.y * scale * wv.y,
                v.z * scale * wv.z, v.w * scale * wv.w);
}

// ---------- GEMM body: C[M,N] = A[M,K] * B[N,K]^T  (bf16 in, OutT out) -----
// BM x BN block tile, BK-deep LDS stage, 4 waves in 2x2, 16x16x32 bf16 MFMA,
// global_load_lds width 16, XOR-swizzled LDS (16B chunks, ^= row & (CPR-1)).
template <int BM, int BN, int BK, typename OutT>
__device__ inline void gemm_body(
    const __hip_bfloat16* __restrict__ A, const __hip_bfloat16* __restrict__ B,
    OutT* __restrict__ C, int M, int N, int K) {
    constexpr int MI = BM / 32;
    constexpr int NJ = BN / 32;
    constexpr int CPR = BK / 8;           // 16B chunks per row
    __shared__ __attribute__((aligned(16))) __hip_bfloat16 lA[BM * BK];
    __shared__ __attribute__((aligned(16))) __hip_bfloat16 lB[BN * BK];
    const int tid  = threadIdx.x;
    const int lane = tid & 63;
    const int wave = tid >> 6;
    const int quad = lane >> 4;
    const int l15  = lane & 15;
    const int wm = (wave >> 1) * (BM / 2);
    const int wn = (wave & 1) * (BN / 2);
    const int m0 = blockIdx.y * BM;
    const int n0 = blockIdx.x * BN;

    float4v acc[MI][NJ] = {};

    for (int k0 = 0; k0 < K; k0 += BK) {
        __syncthreads();
        #pragma unroll
        for (int it = 0; it < BM * CPR / 256; ++it) {
            int p = it * 256 + tid;
            int row = p / CPR;
            int cg = (p & (CPR - 1)) ^ (row & (CPR - 1));
            async_ld16(A + (size_t)(m0 + row) * K + k0 + cg * 8, lA + p * 8);
        }
        #pragma unroll
        for (int it = 0; it < BN * CPR / 256; ++it) {
            int p = it * 256 + tid;
            int row = p / CPR;
            int cg = (p & (CPR - 1)) ^ (row & (CPR - 1));
            async_ld16(B + (size_t)(n0 + row) * K + k0 + cg * 8, lB + p * 8);
        }
        __syncthreads();
        #pragma unroll
        for (int s = 0; s < BK / 32; ++s) {
            short8 af[MI], bfr[NJ];
            #pragma unroll
            for (int i = 0; i < MI; ++i) {
                int r = wm + i * 16 + l15;
                int c = (s * 4 + quad) ^ (r & (CPR - 1));
                af[i] = *(const short8*)(lA + r * BK + c * 8);
            }
            #pragma unroll
            for (int j = 0; j < NJ; ++j) {
                int r = wn + j * 16 + l15;
                int c = (s * 4 + quad) ^ (r & (CPR - 1));
                bfr[j] = *(const short8*)(lB + r * BK + c * 8);
            }
            #pragma unroll
            for (int i = 0; i < MI; ++i)
                #pragma unroll
                for (int j = 0; j < NJ; ++j)
                    acc[i][j] = __builtin_amdgcn_mfma_f32_16x16x32_bf16(
                        af[i], bfr[j], acc[i][j], 0, 0, 0);
        }
    }
    // epilogue: C/D layout col = lane&15, row = quad*4 + reg (m89-verified)
    #pragma unroll
    for (int i = 0; i < MI; ++i)
        #pragma unroll
        for (int j = 0; j < NJ; ++j)
            #pragma unroll
            for (int rg = 0; rg < 4; ++rg) {
                int row = m0 + wm + i * 16 + quad * 4 + rg;
                int col = n0 + wn + j * 16 + l15;
                store_c(C, (size_t)row * N + col, acc[i][j][rg]);
            }
}

__global__ __launch_bounds__(256) void gemm_in(
    const __hip_bfloat16* __restrict__ A, const __hip_bfloat16* __restrict__ B,
    __hip_bfloat16* __restrict__ C, int M, int N, int K) {
    gemm_body<128, 128, 64, __hip_bfloat16>(A, B, C, M, N, K);
}

__global__ __launch_bounds__(256) void gemm_out(
    const __hip_bfloat16* __restrict__ A, const __hip_bfloat16* __restrict__ B,
    float* __restrict__ C, int M, int N, int K) {
    gemm_body<64, 64, 128, float>(A, B, C, M, N, K);
}

// ---------- complex recurrence step: s = a*s + b*u ----------
__device__ inline void cstep(float& sr, float& si, float2 a, float2 bb,
                             uint32_t uw) {
    float ur = bf2f(uw & 0xffffu), ui = bf2f(uw >> 16);
    float tr = bb.x * ur - bb.y * ui;
    float ti = bb.x * ui + bb.y * ur;
    float nr = a.x * sr - a.y * si + tr;
    float ni = a.x * si + a.y * sr + ti;
    sr = nr; si = ni;
}

// ---------- scan pass A: local chunk scans, 4 channels (= one d) / thread ---
__global__ __launch_bounds__(256) void scan_passA(
    const uint4* __restrict__ u4,              // [(b*T+t)*768 + d]
    const float2* __restrict__ ac, const float2* __restrict__ bc,
    float2* __restrict__ chunkEnd) {           // [NCHUNK][NCH]
    int g = blockIdx.x * 256 + threadIdx.x;    // 0..1535
    int j = blockIdx.y;
    int b = g >= DM;
    int d = g - b * DM;
    int cb = d * RR;
    float2 a0 = ac[cb], a1 = ac[cb + 1], a2 = ac[cb + 2], a3 = ac[cb + 3];
    float2 b0 = bc[cb], b1 = bc[cb + 1], b2 = bc[cb + 2], b3 = bc[cb + 3];
    float s0r = 0, s0i = 0, s1r = 0, s1i = 0;
    float s2r = 0, s2i = 0, s3r = 0, s3i = 0;
    size_t base = ((size_t)(b * TT + j * CHUNK)) * DM + d;
    #pragma unroll 4
    for (int i = 0; i < CHUNK; ++i) {
        uint4 uw = u4[base + (size_t)i * DM];
        cstep(s0r, s0i, a0, b0, uw.x);
        cstep(s1r, s1i, a1, b1, uw.y);
        cstep(s2r, s2i, a2, b2, uw.z);
        cstep(s3r, s3i, a3, b3, uw.w);
    }
    size_t eb = (size_t)j * NCH + b * (DM * RR) + cb;
    chunkEnd[eb]     = make_float2(s0r, s0i);
    chunkEnd[eb + 1] = make_float2(s1r, s1i);
    chunkEnd[eb + 2] = make_float2(s2r, s2i);
    chunkEnd[eb + 3] = make_float2(s3r, s3i);
}

// ---------- scan pass B: sequential carry combine (per channel) ----------
__global__ __launch_bounds__(256) void scan_passB(
    const float2* __restrict__ chunkEnd, const float2* __restrict__ aLp,
    float2* __restrict__ carry) {
    int c = blockIdx.x * 256 + threadIdx.x;    // 0..6143
    int rem = (c >= DM * RR) ? c - DM * RR : c;
    float2 aL = aLp[rem];
    float sr = 0.f, si = 0.f;
    for (int j = 0; j < NCHUNK; ++j) {
        carry[(size_t)j * NCH + c] = make_float2(sr, si);
        float2 e = chunkEnd[(size_t)j * NCH + c];
        float nr = aL.x * sr - aL.y * si + e.x;
        float ni = aL.x * si + aL.y * sr + e.y;
        sr = nr; si = ni;
    }
}

// ---------- scan pass C: re-scan with carry, y = sum_r Re(c*s), bf16 out ----
__global__ __launch_bounds__(256) void scan_passC(
    const uint4* __restrict__ u4,
    const float2* __restrict__ ac, const float2* __restrict__ bc,
    const float2* __restrict__ cc, const float2* __restrict__ carry,
    __hip_bfloat16* __restrict__ y) {          // [B*T*D]
    int g = blockIdx.x * 256 + threadIdx.x;
    int j = blockIdx.y;
    int b = g >= DM;
    int d = g - b * DM;
    int cb = d * RR;
    float2 a0 = ac[cb], a1 = ac[cb + 1], a2 = ac[cb + 2], a3 = ac[cb + 3];
    float2 b0 = bc[cb], b1 = bc[cb + 1], b2 = bc[cb + 2], b3 = bc[cb + 3];
    float2 c0 = cc[cb], c1 = cc[cb + 1], c2 = cc[cb + 2], c3 = cc[cb + 3];
    size_t kb = (size_t)j * NCH + b * (DM * RR) + cb;
    float2 k0 = carry[kb], k1 = carry[kb + 1];
    float2 k2 = carry[kb + 2], k3 = carry[kb + 3];
    float s0r = k0.x, s0i = k0.y, s1r = k1.x, s1i = k1.y;
    float s2r = k2.x, s2i = k2.y, s3r = k3.x, s3i = k3.y;
    size_t base  = ((size_t)(b * TT + j * CHUNK)) * DM + d;
    #pragma unroll 4
    for (int i = 0; i < CHUNK; ++i) {
        uint4 uw = u4[base + (size_t)i * DM];
        cstep(s0r, s0i, a0, b0, uw.x);
        cstep(s1r, s1i, a1, b1, uw.y);
        cstep(s2r, s2i, a2, b2, uw.z);
        cstep(s3r, s3i, a3, b3, uw.w);
        float yv = c0.x * s0r - c0.y * s0i + c1.x * s1r - c1.y * s1i
                 + c2.x * s2r - c2.y * s2i + c3.x * s3r - c3.y * s3i;
        y[base + (size_t)i * DM] = __float2bfloat16(yv);
    }
}

// ---------- launch ----------
extern "C" void kernel_launch(void* const* d_in, const int* in_sizes, int n_in,
                              void* d_out, int out_size, void* d_ws,
                              size_t ws_size, hipStream_t stream) {
    const float* x      = (const float*)d_in[0];
    const float* norm_w = (const float*)d_in[1];
    const float* W_in   = (const float*)d_in[2];
    const float* W_out  = (const float*)d_in[3];
    const float* a_p    = (const float*)d_in[4];
    const float* b_p    = (const float*)d_in[5];
    const float* c_p    = (const float*)d_in[6];
    float* out = (float*)d_out;

    char* ws = (char*)d_ws;
    size_t off = 0;
    auto alloc = [&](size_t bytes) {
        void* p = ws + off;
        off += (bytes + 255) & ~(size_t)255;
        return p;
    };
    __hip_bfloat16* Win_bf  = (__hip_bfloat16*)alloc((size_t)NFEAT * DM * 2);
    __hip_bfloat16* Wout_bf = (__hip_bfloat16*)alloc((size_t)DM * DM * 2);
    __hip_bfloat16* xn      = (__hip_bfloat16*)alloc((size_t)M_TOK * DM * 2);
    __hip_bfloat16* u       = (__hip_bfloat16*)alloc((size_t)M_TOK * NFEAT * 2);
    __hip_bfloat16* y       = (__hip_bfloat16*)alloc((size_t)M_TOK * DM * 2);
    float2* ac = (float2*)alloc((size_t)DM * RR * 8);
    float2* bc = (float2*)alloc((size_t)DM * RR * 8);
    float2* cc = (float2*)alloc((size_t)DM * RR * 8);
    float2* aL = (float2*)alloc((size_t)DM * RR * 8);
    float2* chunkEnd = (float2*)alloc((size_t)NCHUNK * NCH * 8);
    float2* carry    = (float2*)alloc((size_t)NCHUNK * NCH * 8);

    // 1. fused weight casts + coefficients (float4-vectorized)
    {
        int n_total = (NFEAT * DM + DM * DM) / 4;
        prep_kernel<<<(n_total + 255) / 256, 256, 0, stream>>>(
            W_in, W_out, a_p, b_p, c_p, Win_bf, Wout_bf, ac, bc, cc, aL);
    }
    // 2. RMSNorm -> bf16
    rmsnorm_kernel<<<M_TOK, 192, 0, stream>>>(x, norm_w, xn);
    // 3. in_proj GEMM: u[4096,6144] = xn @ W_in^T   (128x128, BK=64)
    gemm_in<<<dim3(NFEAT / 128, M_TOK / 128), 256, 0, stream>>>(
        xn, Win_bf, u, M_TOK, NFEAT, DM);
    // 4. chunked scan (A: local, B: carries, C: rescan + emit)
    scan_passA<<<dim3(BATCH * DM / 256, NCHUNK), 256, 0, stream>>>(
        (const uint4*)u, ac, bc, chunkEnd);
    scan_passB<<<NCH / 256, 256, 0, stream>>>(chunkEnd, aL, carry);
    scan_passC<<<dim3(BATCH * DM / 256, NCHUNK), 256, 0, stream>>>(
        (const uint4*)u, ac, bc, cc, carry, y);
    // 5. out_proj GEMM: out[4096,768] = y @ W_out^T (64x64, BK=128)
    gemm_out<<<dim3(DM / 64, M_TOK / 64), 256, 0, stream>>>(
        y, Wout_bf, out, M_TOK, DM, DM);
}